// Round 2
// baseline (439.515 us; speedup 1.0000x reference)
//
#include <hip/hip_runtime.h>

#define IN 906
#define TT 512
#define NB 128

// ---------------------------------------------------------------------------
__device__ __forceinline__ float fsigm(float x) {
    float e = __builtin_amdgcn_exp2f(-1.4426950408889634f * x);   // exp(-x)
    return __builtin_amdgcn_rcpf(1.f + e);
}
__device__ __forceinline__ float ftanh(float x) {
    float e = __builtin_amdgcn_exp2f(-2.8853900817779268f * x);   // exp(-2x)
    return 2.f * __builtin_amdgcn_rcpf(1.f + e) - 1.f;
}
template <int M>
__device__ __forceinline__ float quad_bcast(float v) {
    constexpr int ctrl = M | (M << 2) | (M << 4) | (M << 6);
    return __int_as_float(
        __builtin_amdgcn_mov_dpp(__float_as_int(v), ctrl, 0xf, 0xf, true));
}

// ---------------------------------------------------------------------------
// GEMM: xp = x @ W^T + b1 + b2, stored permuted: xp[row][ (j&3)*4 + (j>>2) ]
// 512 blocks x 256 threads; block -> 128 rows. Register-tiled:
// thread (rg=tid>>2, og=tid&3) computes rows {2rg,2rg+1} x outs {4og..4og+3}.
// x staged column-major in LDS (b64 reads, quad-broadcast); W chunk in LDS
// (b128 reads, 16-lane broadcast). Global loads prefetched into registers.
__global__ __launch_bounds__(256)
void gemm_xp(const float* __restrict__ x, const float* __restrict__ W,
             const float* __restrict__ b1, const float* __restrict__ b2,
             float* __restrict__ xp)
{
    __shared__ float sx[2][32][132];   // [buf][col][row(128)+pad4]
    __shared__ float sw[2][32][16];    // [buf][col][out]
    const int tid = threadIdx.x;
    const size_t rowbase = (size_t)blockIdx.x * 128;

    // x staging map: 2 threads per row, 16 cols each (8 float2)
    const int srow = tid >> 1;
    const int sseg = tid & 1;
    const float* __restrict__ xrow = x + (rowbase + srow) * IN + sseg * 16;
    // W staging map: 16 threads per out-row, 2 cols each
    const int wout = tid >> 4;          // 0..15
    const int wcc  = (tid & 15) * 2;    // 0,2,..,30

    // compute map
    const int rg = tid >> 2;            // 0..63
    const int og = tid & 3;             // 0..3
    const int r0 = rg * 2;

    float2 xr[8];
    float2 wr;
    float acc[2][4];
#pragma unroll
    for (int r = 0; r < 2; ++r)
#pragma unroll
        for (int m = 0; m < 4; ++m) acc[r][m] = 0.f;

    auto load_chunk = [&](int c) {
        const int k0 = c * 32;
        if (c < 28) {
#pragma unroll
            for (int q = 0; q < 8; ++q)
                xr[q] = *(const float2*)(xrow + k0 + q * 2);
            wr = *(const float2*)(W + wout * IN + k0 + wcc);
        } else {                         // tail: cols 896..905 valid
#pragma unroll
            for (int q = 0; q < 8; ++q) {
                int col = k0 + sseg * 16 + q * 2;
                xr[q].x = (col     < IN) ? xrow[k0 + q * 2]     : 0.f;
                xr[q].y = (col + 1 < IN) ? xrow[k0 + q * 2 + 1] : 0.f;
            }
            int colw = k0 + wcc;
            wr.x = (colw     < IN) ? W[wout * IN + colw]     : 0.f;
            wr.y = (colw + 1 < IN) ? W[wout * IN + colw + 1] : 0.f;
        }
    };
    auto write_chunk = [&](int buf) {
#pragma unroll
        for (int q = 0; q < 8; ++q) {
            int cc = sseg * 16 + q * 2;
            sx[buf][cc][srow]     = xr[q].x;
            sx[buf][cc + 1][srow] = xr[q].y;
        }
        sw[buf][wcc][wout]     = wr.x;
        sw[buf][wcc + 1][wout] = wr.y;
    };
    auto compute = [&](int buf) {
#pragma unroll
        for (int cc = 0; cc < 32; ++cc) {
            float2 xv = *(const float2*)&sx[buf][cc][r0];
            float4 wv = *(const float4*)&sw[buf][cc][og * 4];
            acc[0][0] = fmaf(xv.x, wv.x, acc[0][0]);
            acc[0][1] = fmaf(xv.x, wv.y, acc[0][1]);
            acc[0][2] = fmaf(xv.x, wv.z, acc[0][2]);
            acc[0][3] = fmaf(xv.x, wv.w, acc[0][3]);
            acc[1][0] = fmaf(xv.y, wv.x, acc[1][0]);
            acc[1][1] = fmaf(xv.y, wv.y, acc[1][1]);
            acc[1][2] = fmaf(xv.y, wv.z, acc[1][2]);
            acc[1][3] = fmaf(xv.y, wv.w, acc[1][3]);
        }
    };

    load_chunk(0);
    write_chunk(0);
    __syncthreads();
    for (int c = 0; c < 29; ++c) {
        if (c < 28) load_chunk(c + 1);           // global loads in flight...
        compute(c & 1);                          // ...during compute
        if (c < 28) write_chunk((c + 1) & 1);
        __syncthreads();
    }

    // epilogue: out j = og*4+m  ->  permuted pos = m*4 + og
#pragma unroll
    for (int rr = 0; rr < 2; ++rr) {
        const size_t row = rowbase + r0 + rr;
#pragma unroll
        for (int m = 0; m < 4; ++m) {
            int j = og * 4 + m;
            xp[row * 16 + m * 4 + og] = acc[rr][m] + b1[j] + b2[j];
        }
    }
}

// ---------------------------------------------------------------------------
// Recurrence kernel: 8 blocks x 256 threads, 16 batches per block.
// wave 0: 512-step forward recurrence (quad per batch, DPP h-broadcast)
// waves 1-3: backward-direction GEMV (192 lanes = 16 batches x 12 gate rows
//            {i0..3, g0..3, o0..3}; f-gate irrelevant since c0=0) -> LDS
// epilogue (wave 0): backward cell + output projection.
__global__ __launch_bounds__(256)
void frec(const float* __restrict__ xp, const float* __restrict__ x,
          const float* __restrict__ Whh, const float* __restrict__ Wb,
          const float* __restrict__ bb1, const float* __restrict__ bb2,
          const float* __restrict__ Wout, const float* __restrict__ bout,
          float* __restrict__ out)
{
    __shared__ float bg[16][12];
    const int tid = threadIdx.x;

    float h0 = 0.f, h1 = 0.f, h2 = 0.f, h3 = 0.f;

    if (tid >= 64) {
        // ---- backward GEMV ----
        const int gl = tid - 64;          // 0..191
        const int r  = gl >> 4;           // 0..11
        const int bq = gl & 15;
        const int b  = blockIdx.x * 16 + bq;
        const int gr = (r < 4) ? r : r + 4;   // rows: i 0-3, g 8-11, o 12-15
        const float2* __restrict__ xr = (const float2*)(x + ((size_t)b * TT + (TT - 1)) * IN);
        const float2* __restrict__ wrp = (const float2*)(Wb + gr * IN);
        float s0 = 0.f, s1 = 0.f;
        int j = 0;
        for (; j + 8 <= 453; j += 8) {
#pragma unroll
            for (int u = 0; u < 8; ++u) {
                float2 a = xr[j + u];
                float2 w = wrp[j + u];
                s0 = fmaf(a.x, w.x, s0);
                s1 = fmaf(a.y, w.y, s1);
            }
        }
        for (; j < 453; ++j) {
            float2 a = xr[j];
            float2 w = wrp[j];
            s0 = fmaf(a.x, w.x, s0);
            s1 = fmaf(a.y, w.y, s1);
        }
        bg[bq][r] = s0 + s1 + bb1[gr] + bb2[gr];
    } else {
        // ---- forward recurrence ----
        const int k = tid & 3;
        const int b = blockIdx.x * 16 + (tid >> 2);

        float Wi[4], Wf4[4], Wg[4], Wo[4];
#pragma unroll
        for (int m = 0; m < 4; ++m) {
            Wi[m]  = Whh[(k)      * 4 + m];
            Wf4[m] = Whh[(4 + k)  * 4 + m];
            Wg[m]  = Whh[(8 + k)  * 4 + m];
            Wo[m]  = Whh[(12 + k) * 4 + m];
        }

        const float4* __restrict__ xq = (const float4*)xp;
        const size_t base = (size_t)b * TT * 4 + k;

        float4 pf[4];
#pragma unroll
        for (int i = 0; i < 4; ++i) pf[i] = xq[base + (size_t)i * 4];

        float c = 0.f;
        for (int t = 0; t < TT; t += 4) {
#pragma unroll
            for (int u = 0; u < 4; ++u) {
                float4 cur = pf[u];
                int tn = t + 4 + u;
                int tc = (tn < TT) ? tn : (TT - 1);
                pf[u] = xq[base + (size_t)tc * 4];   // prefetch 4 ahead

                float gi = cur.x + h0 * Wi[0]  + h1 * Wi[1]  + h2 * Wi[2]  + h3 * Wi[3];
                float gf = cur.y + h0 * Wf4[0] + h1 * Wf4[1] + h2 * Wf4[2] + h3 * Wf4[3];
                float gg = cur.z + h0 * Wg[0]  + h1 * Wg[1]  + h2 * Wg[2]  + h3 * Wg[3];
                float go = cur.w + h0 * Wo[0]  + h1 * Wo[1]  + h2 * Wo[2]  + h3 * Wo[3];

                float si = fsigm(gi);
                float sf = fsigm(gf);
                float tg = ftanh(gg);
                float so = fsigm(go);

                c = sf * c + si * tg;
                float h = so * ftanh(c);

                h0 = quad_bcast<0>(h);
                h1 = quad_bcast<1>(h);
                h2 = quad_bcast<2>(h);
                h3 = quad_bcast<3>(h);
            }
        }
    }

    __syncthreads();

    if (tid < 64) {
        const int k  = tid & 3;
        const int bq = tid >> 2;
        const int b  = blockIdx.x * 16 + bq;

        // backward cell from GEMV results
        float gib = bg[bq][k];
        float ggb = bg[bq][4 + k];
        float gob = bg[bq][8 + k];
        float hbk = fsigm(gob) * ftanh(fsigm(gib) * ftanh(ggb));
        float hb0 = quad_bcast<0>(hbk);
        float hb1 = quad_bcast<1>(hbk);
        float hb2 = quad_bcast<2>(hbk);
        float hb3 = quad_bcast<3>(hbk);

        float o0 = bout[0]
                 + h0  * Wout[0]  + h1  * Wout[1]  + h2  * Wout[2]  + h3  * Wout[3]
                 + hb0 * Wout[4]  + hb1 * Wout[5]  + hb2 * Wout[6]  + hb3 * Wout[7];
        float o1 = bout[1]
                 + h0  * Wout[8]  + h1  * Wout[9]  + h2  * Wout[10] + h3  * Wout[11]
                 + hb0 * Wout[12] + hb1 * Wout[13] + hb2 * Wout[14] + hb3 * Wout[15];

        if (k == 0) {
            out[b * 2 + 0] = o0;
            out[b * 2 + 1] = o1;
        }
    }
}

// ---------------------------------------------------------------------------
extern "C" void kernel_launch(void* const* d_in, const int* in_sizes, int n_in,
                              void* d_out, int out_size, void* d_ws, size_t ws_size,
                              hipStream_t stream)
{
    const float* x    = (const float*)d_in[0];
    const float* Wihf = (const float*)d_in[1];
    const float* Whhf = (const float*)d_in[2];
    const float* bihf = (const float*)d_in[3];
    const float* bhhf = (const float*)d_in[4];
    const float* Wihb = (const float*)d_in[5];
    const float* bihb = (const float*)d_in[7];
    const float* bhhb = (const float*)d_in[8];
    const float* Wout = (const float*)d_in[9];
    const float* bout = (const float*)d_in[10];

    float* xp = (float*)d_ws;   // 65536 rows x 16 floats = 4,194,304 B exactly

    gemm_xp<<<512, 256, 0, stream>>>(x, Wihf, bihf, bhhf, xp);
    frec<<<8, 256, 0, stream>>>(xp, x, Whhf, Wihb, bihb, bhhb, Wout, bout,
                                (float*)d_out);
}

// Round 4
// 434.832 us; speedup vs baseline: 1.0108x; 1.0108x over previous
//
#include <hip/hip_runtime.h>

#define IN 906
#define TT 512
#define NB 128

// ---------------------------------------------------------------------------
__device__ __forceinline__ float fsigm(float x) {
    float e = __builtin_amdgcn_exp2f(-1.4426950408889634f * x);   // exp(-x)
    return __builtin_amdgcn_rcpf(1.f + e);
}
__device__ __forceinline__ float ftanh(float x) {
    float e = __builtin_amdgcn_exp2f(-2.8853900817779268f * x);   // exp(-2x)
    return 2.f * __builtin_amdgcn_rcpf(1.f + e) - 1.f;
}
template <int M>
__device__ __forceinline__ float quad_bcast(float v) {
    constexpr int ctrl = M | (M << 2) | (M << 4) | (M << 6);
    return __int_as_float(
        __builtin_amdgcn_mov_dpp(__float_as_int(v), ctrl, 0xf, 0xf, true));
}

// ---------------------------------------------------------------------------
// GEMM: xp = x @ W^T + b1 + b2, stored permuted: xp[row][ (j&3)*4 + (j>>2) ]
// (byte-identical to the round-2 passing version)
__global__ __launch_bounds__(256)
void gemm_xp(const float* __restrict__ x, const float* __restrict__ W,
             const float* __restrict__ b1, const float* __restrict__ b2,
             float* __restrict__ xp)
{
    __shared__ float sx[2][32][132];   // [buf][col][row(128)+pad4]
    __shared__ float sw[2][32][16];    // [buf][col][out]
    const int tid = threadIdx.x;
    const size_t rowbase = (size_t)blockIdx.x * 128;

    // x staging map: 2 threads per row, 16 cols each (8 float2)
    const int srow = tid >> 1;
    const int sseg = tid & 1;
    const float* __restrict__ xrow = x + (rowbase + srow) * IN + sseg * 16;
    // W staging map: 16 threads per out-row, 2 cols each
    const int wout = tid >> 4;          // 0..15
    const int wcc  = (tid & 15) * 2;    // 0,2,..,30

    // compute map
    const int rg = tid >> 2;            // 0..63
    const int og = tid & 3;             // 0..3
    const int r0 = rg * 2;

    float2 xr[8];
    float2 wr;
    float acc[2][4];
#pragma unroll
    for (int r = 0; r < 2; ++r)
#pragma unroll
        for (int m = 0; m < 4; ++m) acc[r][m] = 0.f;

    auto load_chunk = [&](int c) {
        const int k0 = c * 32;
        if (c < 28) {
#pragma unroll
            for (int q = 0; q < 8; ++q)
                xr[q] = *(const float2*)(xrow + k0 + q * 2);
            wr = *(const float2*)(W + wout * IN + k0 + wcc);
        } else {                         // tail: cols 896..905 valid
#pragma unroll
            for (int q = 0; q < 8; ++q) {
                int col = k0 + sseg * 16 + q * 2;
                xr[q].x = (col     < IN) ? xrow[k0 + q * 2]     : 0.f;
                xr[q].y = (col + 1 < IN) ? xrow[k0 + q * 2 + 1] : 0.f;
            }
            int colw = k0 + wcc;
            wr.x = (colw     < IN) ? W[wout * IN + colw]     : 0.f;
            wr.y = (colw + 1 < IN) ? W[wout * IN + colw + 1] : 0.f;
        }
    };
    auto write_chunk = [&](int buf) {
#pragma unroll
        for (int q = 0; q < 8; ++q) {
            int cc = sseg * 16 + q * 2;
            sx[buf][cc][srow]     = xr[q].x;
            sx[buf][cc + 1][srow] = xr[q].y;
        }
        sw[buf][wcc][wout]     = wr.x;
        sw[buf][wcc + 1][wout] = wr.y;
    };
    auto compute = [&](int buf) {
#pragma unroll
        for (int cc = 0; cc < 32; ++cc) {
            float2 xv = *(const float2*)&sx[buf][cc][r0];
            float4 wv = *(const float4*)&sw[buf][cc][og * 4];
            acc[0][0] = fmaf(xv.x, wv.x, acc[0][0]);
            acc[0][1] = fmaf(xv.x, wv.y, acc[0][1]);
            acc[0][2] = fmaf(xv.x, wv.z, acc[0][2]);
            acc[0][3] = fmaf(xv.x, wv.w, acc[0][3]);
            acc[1][0] = fmaf(xv.y, wv.x, acc[1][0]);
            acc[1][1] = fmaf(xv.y, wv.y, acc[1][1]);
            acc[1][2] = fmaf(xv.y, wv.z, acc[1][2]);
            acc[1][3] = fmaf(xv.y, wv.w, acc[1][3]);
        }
    };

    load_chunk(0);
    write_chunk(0);
    __syncthreads();
    for (int c = 0; c < 29; ++c) {
        if (c < 28) load_chunk(c + 1);           // global loads in flight...
        compute(c & 1);                          // ...during compute
        if (c < 28) write_chunk((c + 1) & 1);
        __syncthreads();
    }

    // epilogue: out j = og*4+m  ->  permuted pos = m*4 + og
#pragma unroll
    for (int rr = 0; rr < 2; ++rr) {
        const size_t row = rowbase + r0 + rr;
#pragma unroll
        for (int m = 0; m < 4; ++m) {
            int j = og * 4 + m;
            xp[row * 16 + m * 4 + og] = acc[rr][m] + b1[j] + b2[j];
        }
    }
}

// ---------------------------------------------------------------------------
// Recurrence kernel: 8 blocks x 256 threads, 16 batches per block.
// wave 0: 512-step forward recurrence (quad per batch, DPP h-broadcast),
//         16-step-deep xp prefetch (covers ~900cyc cross-XCD/HBM latency;
//         depth 4 left steps memory-throttled at ~225cyc vs ~70cyc chain).
// waves 1-3: backward-direction GEMV (f-gate irrelevant, c0=0) -> LDS.
// epilogue (wave 0): backward cell + output projection.
__global__ __launch_bounds__(256)
void frec(const float* __restrict__ xp, const float* __restrict__ x,
          const float* __restrict__ Whh, const float* __restrict__ Wb,
          const float* __restrict__ bb1, const float* __restrict__ bb2,
          const float* __restrict__ Wout, const float* __restrict__ bout,
          float* __restrict__ out)
{
    __shared__ float bg[16][12];
    const int tid = threadIdx.x;

    float h0 = 0.f, h1 = 0.f, h2 = 0.f, h3 = 0.f;

    if (tid >= 64) {
        // ---- backward GEMV: 192 lanes = 16 batches x 12 gate rows ----
        const int gl = tid - 64;          // 0..191
        const int r  = gl >> 4;           // 0..11
        const int bq = gl & 15;
        const int b  = blockIdx.x * 16 + bq;
        const int gr = (r < 4) ? r : r + 4;   // rows: i 0-3, g 8-11, o 12-15
        const float2* __restrict__ xr  = (const float2*)(x + ((size_t)b * TT + (TT - 1)) * IN);
        const float2* __restrict__ wrp = (const float2*)(Wb + gr * IN);
        float s0 = 0.f, s1 = 0.f;
        int j = 0;
        for (; j + 8 <= 453; j += 8) {
#pragma unroll
            for (int u = 0; u < 8; ++u) {
                float2 a = xr[j + u];
                float2 w = wrp[j + u];
                s0 = fmaf(a.x, w.x, s0);
                s1 = fmaf(a.y, w.y, s1);
            }
        }
        for (; j < 453; ++j) {
            float2 a = xr[j];
            float2 w = wrp[j];
            s0 = fmaf(a.x, w.x, s0);
            s1 = fmaf(a.y, w.y, s1);
        }
        bg[bq][r] = s0 + s1 + bb1[gr] + bb2[gr];
    } else {
        // ---- forward recurrence ----
        const int k = tid & 3;
        const int b = blockIdx.x * 16 + (tid >> 2);

        float Wi[4], Wf4[4], Wg[4], Wo[4];
#pragma unroll
        for (int m = 0; m < 4; ++m) {
            Wi[m]  = Whh[(k)      * 4 + m];
            Wf4[m] = Whh[(4 + k)  * 4 + m];
            Wg[m]  = Whh[(8 + k)  * 4 + m];
            Wo[m]  = Whh[(12 + k) * 4 + m];
        }

        const float4* __restrict__ xq = (const float4*)xp;
        const size_t base = (size_t)b * TT * 4 + k;

        float4 pf[16];
#pragma unroll
        for (int i = 0; i < 16; ++i) pf[i] = xq[base + (size_t)i * 4];

        float c = 0.f;
        for (int t = 0; t < TT; t += 16) {
#pragma unroll
            for (int u = 0; u < 16; ++u) {
                float4 cur = pf[u];
                int tn = t + 16 + u;
                int tc = (tn < TT) ? tn : (TT - 1);
                pf[u] = xq[base + (size_t)tc * 4];   // prefetch 16 ahead

                float gi = cur.x + h0 * Wi[0]  + h1 * Wi[1]  + h2 * Wi[2]  + h3 * Wi[3];
                float gf = cur.y + h0 * Wf4[0] + h1 * Wf4[1] + h2 * Wf4[2] + h3 * Wf4[3];
                float gg = cur.z + h0 * Wg[0]  + h1 * Wg[1]  + h2 * Wg[2]  + h3 * Wg[3];
                float go = cur.w + h0 * Wo[0]  + h1 * Wo[1]  + h2 * Wo[2]  + h3 * Wo[3];

                float si = fsigm(gi);
                float sf = fsigm(gf);
                float tg = ftanh(gg);
                float so = fsigm(go);

                c = sf * c + si * tg;
                float h = so * ftanh(c);

                h0 = quad_bcast<0>(h);
                h1 = quad_bcast<1>(h);
                h2 = quad_bcast<2>(h);
                h3 = quad_bcast<3>(h);
            }
        }
    }

    __syncthreads();

    if (tid < 64) {
        const int k  = tid & 3;
        const int bq = tid >> 2;
        const int b  = blockIdx.x * 16 + bq;

        float gib = bg[bq][k];
        float ggb = bg[bq][4 + k];
        float gob = bg[bq][8 + k];
        float hbk = fsigm(gob) * ftanh(fsigm(gib) * ftanh(ggb));
        float hb0 = quad_bcast<0>(hbk);
        float hb1 = quad_bcast<1>(hbk);
        float hb2 = quad_bcast<2>(hbk);
        float hb3 = quad_bcast<3>(hbk);

        float o0 = bout[0]
                 + h0  * Wout[0]  + h1  * Wout[1]  + h2  * Wout[2]  + h3  * Wout[3]
                 + hb0 * Wout[4]  + hb1 * Wout[5]  + hb2 * Wout[6]  + hb3 * Wout[7];
        float o1 = bout[1]
                 + h0  * Wout[8]  + h1  * Wout[9]  + h2  * Wout[10] + h3  * Wout[11]
                 + hb0 * Wout[12] + hb1 * Wout[13] + hb2 * Wout[14] + hb3 * Wout[15];

        if (k == 0) {
            out[b * 2 + 0] = o0;
            out[b * 2 + 1] = o1;
        }
    }
}

// ---------------------------------------------------------------------------
extern "C" void kernel_launch(void* const* d_in, const int* in_sizes, int n_in,
                              void* d_out, int out_size, void* d_ws, size_t ws_size,
                              hipStream_t stream)
{
    const float* x    = (const float*)d_in[0];
    const float* Wihf = (const float*)d_in[1];
    const float* Whhf = (const float*)d_in[2];
    const float* bihf = (const float*)d_in[3];
    const float* bhhf = (const float*)d_in[4];
    const float* Wihb = (const float*)d_in[5];
    const float* bihb = (const float*)d_in[7];
    const float* bhhb = (const float*)d_in[8];
    const float* Wout = (const float*)d_in[9];
    const float* bout = (const float*)d_in[10];

    float* xp = (float*)d_ws;   // 65536 rows x 16 floats = 4,194,304 B exactly

    gemm_xp<<<512, 256, 0, stream>>>(x, Wihf, bihf, bhhf, xp);
    frec<<<8, 256, 0, stream>>>(xp, x, Whhf, Wihb, bihb, bhhb, Wout, bout,
                                (float*)d_out);
}